// Round 1
// baseline (316.093 us; speedup 1.0000x reference)
//
#include <hip/hip_runtime.h>
#include <math.h>

#define N_ 32
#define T_ 2048
#define E_ 512
#define D_ 1024
#define U_ 256

typedef __attribute__((ext_vector_type(8))) short bf16x8;
typedef __attribute__((ext_vector_type(16))) float f32x16;

__device__ __forceinline__ short f2bf_rne(float x) {
  unsigned int u = __float_as_uint(x);
  unsigned int r = u + 0x7FFFu + ((u >> 16) & 1u);
  return (short)(r >> 16);
}
__device__ __forceinline__ short f2bf_trunc(float x) {
  return (short)(__float_as_uint(x) >> 16);
}
__device__ __forceinline__ float bf2f(short h) {
  return __uint_as_float(((unsigned int)(unsigned short)h) << 16);
}
// tanh via hw exp2+rcp: tanh(x) = 1 - 2/(e^{2x}+1); saturates correctly at +-inf
__device__ __forceinline__ float fast_tanh(float x) {
  float t = exp2f(x * 2.8853900817779268f);   // e^{2x}, v_exp_f32
  return 1.0f - 2.0f * __builtin_amdgcn_rcpf(t + 1.0f);
}
__device__ __forceinline__ float fast_sigmoid(float w) {
  return __builtin_amdgcn_rcpf(1.0f + exp2f(-1.4426950408889634f * w));
}

// ---------------- K1: Wk -> bf16 hi/lo B-fragments (WGs 0..63)
//                 + proj_q partials (WGs 64..191) ----------------
// frag f = ((c*4+kc)*8+ub)*64+lane : u = ub*32+(lane&31), e = c*64+kc*16+(lane>>5)*8+j
__global__ __launch_bounds__(256) void prep_kernel(
    const float* __restrict__ Wk, const float* __restrict__ queries,
    const float* __restrict__ Wq, bf16x8* __restrict__ whiP,
    bf16x8* __restrict__ wloP, float* __restrict__ pq_part) {
  const int wg = blockIdx.x, tid = threadIdx.x;
  if (wg < 64) {
    const int fid = wg * 256 + tid;
    const int lane = fid & 63;
    const int ub = (fid >> 6) & 7;
    const int kc = (fid >> 9) & 3;
    const int c = fid >> 11;
    const int u = ub * 32 + (lane & 31);
    const int e0 = c * 64 + kc * 16 + (lane >> 5) * 8;
    bf16x8 H, L;
#pragma unroll
    for (int j = 0; j < 8; ++j) {
      float x = Wk[(size_t)(e0 + j) * U_ + u];   // lanes&31 consecutive over u
      short h = f2bf_trunc(x);
      H[j] = h;
      L[j] = f2bf_rne(x - bf2f(h));
    }
    whiP[fid] = H;
    wloP[fid] = L;
  } else {
    const int ch = (wg - 64) & 3;
    const int bb = (wg - 64) >> 2;
    const int d0 = ch * 256;
    const float* q = queries + bb * D_ + d0;
    const float* wq = Wq + (size_t)d0 * U_ + tid;
    float acc = 0.f;
#pragma unroll 8
    for (int d = 0; d < 256; ++d)
      acc = fmaf(q[d], wq[(size_t)d * U_], acc);   // q[d] wave-uniform
    pq_part[(bb * 4 + ch) * U_ + tid] = acc;
  }
}

// ---------------- K2: score via split-bf16 MFMA, barrier-free ----------------
// Grid 512 (T/128 x N); WG 256 = 4 waves; WG tile 128t x 256u; wave 128t x 64u
// = 4x2 mfma_f32_32x32x16_bf16, 3-product hi/lo split (acc[4][2] = 128 AGPRs).
// A-fragments are loaded DIRECTLY from global: lane l of a 32x32x16 A-frag needs
// A[row=l&31, k=(l>>5)*8+j] = 32 contiguous bytes of one memory row (lanes l,l+32
// cover a contiguous 64B). No LDS staging -> no __syncthreads in the main loop,
// no vmcnt(0)-at-barrier drain, no bank conflicts; the 4 waves/WG re-read the
// same 8KB/step through L1. fp32->bf16 hi/lo split happens at frag-read time in
// the MFMA shadow. Accumulation order identical to the staged version.
__global__ __launch_bounds__(256, 2) void score_kernel(
    const float* __restrict__ memory, const bf16x8* __restrict__ whiP,
    const bf16x8* __restrict__ wloP, const float* __restrict__ pq_part,
    const float* __restrict__ v, float* __restrict__ p_choose) {
  __shared__ float smem_w[4][128];

  const int b = blockIdx.y;
  const int t0 = blockIdx.x * 128;
  const int tid = threadIdx.x;
  const int lane = tid & 63;
  const int ty = tid >> 6;
  const int l31 = lane & 31;
  const int half = lane >> 5;

  f32x16 acc[4][2];
#pragma unroll
  for (int mt = 0; mt < 4; ++mt)
#pragma unroll
    for (int nt = 0; nt < 2; ++nt)
#pragma unroll
      for (int r = 0; r < 16; ++r) acc[mt][nt][r] = 0.f;

  // per-lane A base: row = t0 + mt*32 + l31, e-offset = half*8 (+ step*16)
  const float* aptr = memory + ((size_t)(b * T_ + t0 + l31)) * E_ + half * 8;
  // B frag base for this wave: full fidx = (step*8 + ty*2 + nt)*64 + lane
  const bf16x8* bhp = whiP + (size_t)(ty * 2) * 64 + lane;
  const bf16x8* blp = wloP + (size_t)(ty * 2) * 64 + lane;

#pragma unroll 2
  for (int step = 0; step < 32; ++step) {
    // ---- loads first (A: 8x float4, B: 4x 16B) so they can pipeline ----
    float4 a0[4], a1[4];
#pragma unroll
    for (int mt = 0; mt < 4; ++mt) {
      const float* p = aptr + (size_t)mt * (32 * E_) + step * 16;
      a0[mt] = *(const float4*)(p);
      a1[mt] = *(const float4*)(p + 4);
    }
    bf16x8 bh[2], bl[2];
#pragma unroll
    for (int nt = 0; nt < 2; ++nt) {
      bh[nt] = bhp[(size_t)(step * 8 + nt) * 64];
      bl[nt] = blp[(size_t)(step * 8 + nt) * 64];
    }
    // ---- split-bf16 conversion (same math/order as staged version) ----
    bf16x8 ah[4], al[4];
#pragma unroll
    for (int mt = 0; mt < 4; ++mt) {
      float xs[8] = {a0[mt].x, a0[mt].y, a0[mt].z, a0[mt].w,
                     a1[mt].x, a1[mt].y, a1[mt].z, a1[mt].w};
#pragma unroll
      for (int i = 0; i < 8; ++i) {
        short h = f2bf_trunc(xs[i]);
        ah[mt][i] = h;
        al[mt][i] = f2bf_rne(xs[i] - bf2f(h));
      }
    }
    // ---- 24 MFMAs ----
#pragma unroll
    for (int mt = 0; mt < 4; ++mt)
#pragma unroll
      for (int nt = 0; nt < 2; ++nt) {
        acc[mt][nt] = __builtin_amdgcn_mfma_f32_32x32x16_bf16(ah[mt], bh[nt], acc[mt][nt], 0, 0, 0);
        acc[mt][nt] = __builtin_amdgcn_mfma_f32_32x32x16_bf16(ah[mt], bl[nt], acc[mt][nt], 0, 0, 0);
        acc[mt][nt] = __builtin_amdgcn_mfma_f32_32x32x16_bf16(al[mt], bh[nt], acc[mt][nt], 0, 0, 0);
      }
  }

  // epilogue: w[t] = sum_u tanh(score + pq[u]) * v[u]; p = sigmoid(w)
  const int u0 = ty * 64 + l31;
  const int u1 = u0 + 32;
  float pq0 = 0.f, pq1 = 0.f;
#pragma unroll
  for (int c = 0; c < 4; ++c) {
    pq0 += pq_part[(b * 4 + c) * U_ + u0];
    pq1 += pq_part[(b * 4 + c) * U_ + u1];
  }
  const float v0 = v[u0], v1 = v[u1];
#pragma unroll
  for (int mt = 0; mt < 4; ++mt)
#pragma unroll
    for (int r = 0; r < 16; ++r) {
      float s = fast_tanh(acc[mt][0][r] + pq0) * v0 + fast_tanh(acc[mt][1][r] + pq1) * v1;
#pragma unroll
      for (int off = 1; off < 32; off <<= 1) s += __shfl_xor(s, off, 64);
      if (l31 == 0) {
        const int row = mt * 32 + (r & 3) + 8 * (r >> 2) + 4 * half;
        smem_w[ty][row] = s;
      }
    }
  __syncthreads();
  if (tid < 128) {
    const float w = smem_w[0][tid] + smem_w[1][tid] + smem_w[2][tid] + smem_w[3][tid];
    p_choose[b * T_ + t0 + tid] = fast_sigmoid(w);
  }
}

// ---------------- K3: monotonic scan per batch row + zero ctx_out ----------------
__device__ __forceinline__ float block_incl_scan(float val, float* sbuf, int tid) {
  float x = val;
  sbuf[tid] = x;
  __syncthreads();
#pragma unroll
  for (int off = 1; off < 256; off <<= 1) {
    float t = (tid >= off) ? sbuf[tid - off] : 0.f;
    __syncthreads();
    x += t;
    sbuf[tid] = x;
    __syncthreads();
  }
  return x;
}

__global__ __launch_bounds__(256) void scan_kernel(
    const float* __restrict__ p_choose, const float* __restrict__ prev,
    float* __restrict__ align_out, float* __restrict__ ctx_out) {
  __shared__ float sbuf[256];
  const int b = blockIdx.x, tid = threadIdx.x;
  // zero this batch's ctx row (d_out is poisoned before every call)
  ctx_out[b * E_ + tid] = 0.f;
  ctx_out[b * E_ + 256 + tid] = 0.f;
  const int base = b * T_ + tid * 8;
  float4 p0 = *(const float4*)(p_choose + base);
  float4 p1 = *(const float4*)(p_choose + base + 4);
  float p[8] = {p0.x, p0.y, p0.z, p0.w, p1.x, p1.y, p1.z, p1.w};
  float s[8];
  float run = 0.f;
#pragma unroll
  for (int k = 0; k < 8; ++k) {
    float x = 1.0f - p[k];
    x = fminf(fmaxf(x, 1e-20f), 1.0f);
    run += logf(x);
    s[k] = run;
  }
  float incl = block_incl_scan(run, sbuf, tid);
  float excl = incl - run;
  float cp[8];
#pragma unroll
  for (int k = 0; k < 8; ++k)
    cp[k] = expf(excl + (k ? s[k - 1] : 0.f));
  float4 r0 = *(const float4*)(prev + base);
  float4 r1 = *(const float4*)(prev + base + 4);
  float pr[8] = {r0.x, r0.y, r0.z, r0.w, r1.x, r1.y, r1.z, r1.w};
  float s2[8];
  float run2 = 0.f;
#pragma unroll
  for (int k = 0; k < 8; ++k) {
    float d = fminf(fmaxf(cp[k], 1e-10f), 1.0f);
    run2 += pr[k] / d;
    s2[k] = run2;
  }
  float incl2 = block_incl_scan(run2, sbuf, tid);
  float excl2 = incl2 - run2;
#pragma unroll
  for (int k = 0; k < 8; ++k)
    p[k] = p[k] * cp[k] * (excl2 + s2[k]);
  *(float4*)(align_out + base) = make_float4(p[0], p[1], p[2], p[3]);
  *(float4*)(align_out + base + 4) = make_float4(p[4], p[5], p[6], p[7]);
}

// ---------------- K4: contexts = alignments . memory (atomic accumulate) ----------
// 512 WGs: wg -> (b, 128-row chunk); each half-WG does 64 rows x full E.
// Unroll-4 with batched loads: 4 float4 + 4 align scalars in flight per thread.
__global__ __launch_bounds__(256) void ctx_kernel(
    const float* __restrict__ memory, const float* __restrict__ align,
    float* __restrict__ ctx_out) {
  const int wg = blockIdx.x, tid = threadIdx.x;
  const int b = wg >> 4;
  const int t0 = (wg & 15) * 128 + (tid >> 7) * 64;
  const int col = (tid & 127) * 4;
  const float* mrow = memory + ((size_t)(b * T_ + t0)) * E_ + col;
  const float* arow = align + b * T_ + t0;
  float4 a = make_float4(0.f, 0.f, 0.f, 0.f);
  for (int t = 0; t < 64; t += 4) {
    float4 m0 = *(const float4*)(mrow + (size_t)(t + 0) * E_);
    float4 m1 = *(const float4*)(mrow + (size_t)(t + 1) * E_);
    float4 m2 = *(const float4*)(mrow + (size_t)(t + 2) * E_);
    float4 m3 = *(const float4*)(mrow + (size_t)(t + 3) * E_);
    float a0 = arow[t], a1 = arow[t + 1], a2 = arow[t + 2], a3 = arow[t + 3];
    a.x = fmaf(a0, m0.x, a.x); a.y = fmaf(a0, m0.y, a.y);
    a.z = fmaf(a0, m0.z, a.z); a.w = fmaf(a0, m0.w, a.w);
    a.x = fmaf(a1, m1.x, a.x); a.y = fmaf(a1, m1.y, a.y);
    a.z = fmaf(a1, m1.z, a.z); a.w = fmaf(a1, m1.w, a.w);
    a.x = fmaf(a2, m2.x, a.x); a.y = fmaf(a2, m2.y, a.y);
    a.z = fmaf(a2, m2.z, a.z); a.w = fmaf(a2, m2.w, a.w);
    a.x = fmaf(a3, m3.x, a.x); a.y = fmaf(a3, m3.y, a.y);
    a.z = fmaf(a3, m3.z, a.z); a.w = fmaf(a3, m3.w, a.w);
  }
  float* dst = ctx_out + b * E_ + col;
  atomicAdd(dst + 0, a.x);
  atomicAdd(dst + 1, a.y);
  atomicAdd(dst + 2, a.z);
  atomicAdd(dst + 3, a.w);
}

// ---------------- launch ----------------
extern "C" void kernel_launch(void* const* d_in, const int* in_sizes, int n_in,
                              void* d_out, int out_size, void* d_ws, size_t ws_size,
                              hipStream_t stream) {
  (void)in_sizes; (void)n_in; (void)out_size; (void)ws_size;
  const float* queries = (const float*)d_in[0];
  const float* prev    = (const float*)d_in[1];
  const float* memory  = (const float*)d_in[2];
  const float* Wq      = (const float*)d_in[3];
  const float* Wk      = (const float*)d_in[4];
  const float* v       = (const float*)d_in[5];

  float* out = (float*)d_out;
  float* ctx_out = out;              // [N,E]
  float* align_out = out + N_ * E_;  // [N,T]

  // ws layout (float slots): whiP [0,65536)  wloP [65536,131072)
  //   p_choose [131072,196608)  pq_part [196608,200704)
  float* ws = (float*)d_ws;
  bf16x8* whiP    = (bf16x8*)ws;
  bf16x8* wloP    = (bf16x8*)(ws + 65536);
  float* p_choose = ws + 131072;
  float* pq_part  = ws + 196608;

  prep_kernel<<<dim3(64 + 128), 256, 0, stream>>>(Wk, queries, Wq, whiP, wloP, pq_part);
  score_kernel<<<dim3(T_ / 128, N_), 256, 0, stream>>>(memory, whiP, wloP, pq_part, v, p_choose);
  scan_kernel<<<dim3(N_), 256, 0, stream>>>(p_choose, prev, align_out, ctx_out);
  ctx_kernel<<<dim3(512), 256, 0, stream>>>(memory, align_out, ctx_out);
}

// Round 2
// 268.779 us; speedup vs baseline: 1.1760x; 1.1760x over previous
//
#include <hip/hip_runtime.h>
#include <math.h>

#define N_ 32
#define T_ 2048
#define E_ 512
#define D_ 1024
#define U_ 256

typedef __attribute__((ext_vector_type(8))) short bf16x8;
typedef __attribute__((ext_vector_type(16))) float f32x16;

__device__ __forceinline__ short f2bf_rne(float x) {
  unsigned int u = __float_as_uint(x);
  unsigned int r = u + 0x7FFFu + ((u >> 16) & 1u);
  return (short)(r >> 16);
}
__device__ __forceinline__ short f2bf_trunc(float x) {
  return (short)(__float_as_uint(x) >> 16);
}
__device__ __forceinline__ float bf2f(short h) {
  return __uint_as_float(((unsigned int)(unsigned short)h) << 16);
}
// tanh via hw exp2+rcp: tanh(x) = 1 - 2/(e^{2x}+1); saturates correctly at +-inf
__device__ __forceinline__ float fast_tanh(float x) {
  float t = exp2f(x * 2.8853900817779268f);   // e^{2x}, v_exp_f32
  return 1.0f - 2.0f * __builtin_amdgcn_rcpf(t + 1.0f);
}
__device__ __forceinline__ float fast_sigmoid(float w) {
  return __builtin_amdgcn_rcpf(1.0f + exp2f(-1.4426950408889634f * w));
}

// ---------------- K1: Wk -> bf16 hi/lo B-fragments (WGs 0..63)
//                 + proj_q partials (WGs 64..191) ----------------
// frag f = (kk*8+ub)*64+lane : u = ub*32+(lane&31), e = kk*16+(lane>>5)*8+j, kk=0..31
__global__ __launch_bounds__(256) void prep_kernel(
    const float* __restrict__ Wk, const float* __restrict__ queries,
    const float* __restrict__ Wq, bf16x8* __restrict__ whiP,
    bf16x8* __restrict__ wloP, float* __restrict__ pq_part) {
  const int wg = blockIdx.x, tid = threadIdx.x;
  if (wg < 64) {
    const int fid = wg * 256 + tid;
    const int lane = fid & 63;
    const int ub = (fid >> 6) & 7;
    const int kc = (fid >> 9) & 3;
    const int c = fid >> 11;
    const int u = ub * 32 + (lane & 31);
    const int e0 = c * 64 + kc * 16 + (lane >> 5) * 8;
    bf16x8 H, L;
#pragma unroll
    for (int j = 0; j < 8; ++j) {
      float x = Wk[(size_t)(e0 + j) * U_ + u];   // lanes&31 consecutive over u
      short h = f2bf_trunc(x);
      H[j] = h;
      L[j] = f2bf_rne(x - bf2f(h));
    }
    whiP[fid] = H;
    wloP[fid] = L;
  } else {
    const int ch = (wg - 64) & 3;
    const int bb = (wg - 64) >> 2;
    const int d0 = ch * 256;
    const float* q = queries + bb * D_ + d0;
    const float* wq = Wq + (size_t)d0 * U_ + tid;
    float acc = 0.f;
#pragma unroll 8
    for (int d = 0; d < 256; ++d)
      acc = fmaf(q[d], wq[(size_t)d * U_], acc);   // q[d] wave-uniform
    pq_part[(bb * 4 + ch) * U_ + tid] = acc;
  }
}

// ---------------- K2: score via split-bf16 MFMA, pipelined LDS staging --------
// Grid 512 (T/128 x N); WG 256 = 4 waves; WG tile 128t x 256u; wave 128t x 64u
// = 4x2 mfma_f32_32x32x16_bf16, 3-product hi/lo split (acc[4][2] = 128 AGPRs).
// Staging is COALESCED (2 threads per 128B row segment) into LDS, converted
// fp32->bf16 hi/lo once per WG. vs round-0: the staging loads for tile it+1 are
// issued BEFORE compute(it) and written to the other of 2 LDS buffers AFTER it
// (HBM latency ~900cy hides under ~600cy of MFMA+frag-reads). 32-col K-steps
// (16 iters) keep in-flight prefetch at 16 VGPRs so VGPR+AGPR stays <=256
// (2 waves/SIMD). One barrier per iter (was 2). hi|lo packed in one 128B LDS
// row, 8x16B slots, slot XOR (row&7) swizzle — same as round-0, bit-identical
// accumulation order.
__global__ __launch_bounds__(256, 2) void score_kernel(
    const float* __restrict__ memory, const bf16x8* __restrict__ whiP,
    const bf16x8* __restrict__ wloP, const float* __restrict__ pq_part,
    const float* __restrict__ v, float* __restrict__ p_choose) {
  __shared__ short sA[2][128 * 64];   // per buf: 128 rows x (hi[32]|lo[32]) = 128B/row, 16KB
  __shared__ float smem_w[4][128];

  const int b = blockIdx.y;
  const int t0 = blockIdx.x * 128;
  const int tid = threadIdx.x;
  const int lane = tid & 63;
  const int ty = tid >> 6;
  const int l31 = lane & 31;
  const int half = lane >> 5;

  f32x16 acc[4][2];
#pragma unroll
  for (int mt = 0; mt < 4; ++mt)
#pragma unroll
    for (int nt = 0; nt < 2; ++nt)
#pragma unroll
      for (int r = 0; r < 16; ++r) acc[mt][nt][r] = 0.f;

  // staging: thread -> row sr = tid>>1, col-half cs = (tid&1)*16 of the 32-col step
  const int sr = tid >> 1;
  const int cs = (tid & 1) * 16;
  const int s0 = cs >> 3;                    // logical hi slot base: 0 or 2
  const int sw = sr & 7;
  const float* srow = memory + ((size_t)(b * T_ + t0 + sr)) * E_ + cs;
  char* const bp0 = (char*)&sA[0][0] + sr * 128;
  char* const bp1 = (char*)&sA[1][0] + sr * 128;

  float4 xr[4];
#pragma unroll
  for (int j = 0; j < 4; ++j) xr[j] = *(const float4*)(srow + j * 4);

  auto do_stage = [&](char* bp) {
    float xs[16] = {xr[0].x, xr[0].y, xr[0].z, xr[0].w,
                    xr[1].x, xr[1].y, xr[1].z, xr[1].w,
                    xr[2].x, xr[2].y, xr[2].z, xr[2].w,
                    xr[3].x, xr[3].y, xr[3].z, xr[3].w};
    bf16x8 H0, H1, L0, L1;
#pragma unroll
    for (int i = 0; i < 8; ++i) {
      short h0 = f2bf_trunc(xs[i]);
      H0[i] = h0;
      L0[i] = f2bf_rne(xs[i] - bf2f(h0));
      short h1 = f2bf_trunc(xs[8 + i]);
      H1[i] = h1;
      L1[i] = f2bf_rne(xs[8 + i] - bf2f(h1));
    }
    *(bf16x8*)(bp + (((s0 + 0) ^ sw) * 16)) = H0;
    *(bf16x8*)(bp + (((s0 + 1) ^ sw) * 16)) = H1;
    *(bf16x8*)(bp + (((s0 + 4) ^ sw) * 16)) = L0;
    *(bf16x8*)(bp + (((s0 + 5) ^ sw) * 16)) = L1;
  };

  do_stage(bp0);
  __syncthreads();

  int cur = 0;
  for (int it = 0; it < 16; ++it) {
    // prefetch next tile's globals (consumed after compute, in do_stage)
    if (it < 15) {
      const float* src = srow + (it + 1) * 32;
#pragma unroll
      for (int j = 0; j < 4; ++j) xr[j] = *(const float4*)(src + j * 4);
    }
    const char* base = (const char*)&sA[cur][0];
#pragma unroll
    for (int kc = 0; kc < 2; ++kc) {
      bf16x8 bh[2], bl[2];
#pragma unroll
      for (int nt = 0; nt < 2; ++nt) {
        const int fidx = ((it * 2 + kc) * 8 + (ty * 2 + nt)) * 64 + lane;
        bh[nt] = whiP[fidx];
        bl[nt] = wloP[fidx];
      }
      const int sl = kc * 2 + half;
      bf16x8 ah[4], al[4];
#pragma unroll
      for (int mt = 0; mt < 4; ++mt) {
        const int m = mt * 32 + l31;
        ah[mt] = *(const bf16x8*)(base + (size_t)m * 128 + ((sl ^ (m & 7)) * 16));
        al[mt] = *(const bf16x8*)(base + (size_t)m * 128 + (((sl + 4) ^ (m & 7)) * 16));
      }
#pragma unroll
      for (int mt = 0; mt < 4; ++mt)
#pragma unroll
        for (int nt = 0; nt < 2; ++nt) {
          acc[mt][nt] = __builtin_amdgcn_mfma_f32_32x32x16_bf16(ah[mt], bh[nt], acc[mt][nt], 0, 0, 0);
          acc[mt][nt] = __builtin_amdgcn_mfma_f32_32x32x16_bf16(ah[mt], bl[nt], acc[mt][nt], 0, 0, 0);
          acc[mt][nt] = __builtin_amdgcn_mfma_f32_32x32x16_bf16(al[mt], bh[nt], acc[mt][nt], 0, 0, 0);
        }
    }
    // write next tile into the other buffer; its readers (iter it-1) are past
    // the barrier at end of it-1, and compute(it) only touched sA[cur].
    if (it < 15) do_stage(cur ? bp0 : bp1);
    __syncthreads();
    cur ^= 1;
  }

  // epilogue: w[t] = sum_u tanh(score + pq[u]) * v[u]; p = sigmoid(w)
  const int u0 = ty * 64 + l31;
  const int u1 = u0 + 32;
  float pq0 = 0.f, pq1 = 0.f;
#pragma unroll
  for (int c = 0; c < 4; ++c) {
    pq0 += pq_part[(b * 4 + c) * U_ + u0];
    pq1 += pq_part[(b * 4 + c) * U_ + u1];
  }
  const float v0 = v[u0], v1 = v[u1];
#pragma unroll
  for (int mt = 0; mt < 4; ++mt)
#pragma unroll
    for (int r = 0; r < 16; ++r) {
      float s = fast_tanh(acc[mt][0][r] + pq0) * v0 + fast_tanh(acc[mt][1][r] + pq1) * v1;
#pragma unroll
      for (int off = 1; off < 32; off <<= 1) s += __shfl_xor(s, off, 64);
      if (l31 == 0) {
        const int row = mt * 32 + (r & 3) + 8 * (r >> 2) + 4 * half;
        smem_w[ty][row] = s;
      }
    }
  __syncthreads();
  if (tid < 128) {
    const float w = smem_w[0][tid] + smem_w[1][tid] + smem_w[2][tid] + smem_w[3][tid];
    p_choose[b * T_ + t0 + tid] = fast_sigmoid(w);
  }
}

// ---------------- K3: monotonic scan per batch row + zero ctx_out ----------------
__device__ __forceinline__ float block_incl_scan(float val, float* sbuf, int tid) {
  float x = val;
  sbuf[tid] = x;
  __syncthreads();
#pragma unroll
  for (int off = 1; off < 256; off <<= 1) {
    float t = (tid >= off) ? sbuf[tid - off] : 0.f;
    __syncthreads();
    x += t;
    sbuf[tid] = x;
    __syncthreads();
  }
  return x;
}

__global__ __launch_bounds__(256) void scan_kernel(
    const float* __restrict__ p_choose, const float* __restrict__ prev,
    float* __restrict__ align_out, float* __restrict__ ctx_out) {
  __shared__ float sbuf[256];
  const int b = blockIdx.x, tid = threadIdx.x;
  // zero this batch's ctx row (d_out is poisoned before every call)
  ctx_out[b * E_ + tid] = 0.f;
  ctx_out[b * E_ + 256 + tid] = 0.f;
  const int base = b * T_ + tid * 8;
  float4 p0 = *(const float4*)(p_choose + base);
  float4 p1 = *(const float4*)(p_choose + base + 4);
  float p[8] = {p0.x, p0.y, p0.z, p0.w, p1.x, p1.y, p1.z, p1.w};
  float s[8];
  float run = 0.f;
#pragma unroll
  for (int k = 0; k < 8; ++k) {
    float x = 1.0f - p[k];
    x = fminf(fmaxf(x, 1e-20f), 1.0f);
    run += logf(x);
    s[k] = run;
  }
  float incl = block_incl_scan(run, sbuf, tid);
  float excl = incl - run;
  float cp[8];
#pragma unroll
  for (int k = 0; k < 8; ++k)
    cp[k] = expf(excl + (k ? s[k - 1] : 0.f));
  float4 r0 = *(const float4*)(prev + base);
  float4 r1 = *(const float4*)(prev + base + 4);
  float pr[8] = {r0.x, r0.y, r0.z, r0.w, r1.x, r1.y, r1.z, r1.w};
  float s2[8];
  float run2 = 0.f;
#pragma unroll
  for (int k = 0; k < 8; ++k) {
    float d = fminf(fmaxf(cp[k], 1e-10f), 1.0f);
    run2 += pr[k] / d;
    s2[k] = run2;
  }
  float incl2 = block_incl_scan(run2, sbuf, tid);
  float excl2 = incl2 - run2;
#pragma unroll
  for (int k = 0; k < 8; ++k)
    p[k] = p[k] * cp[k] * (excl2 + s2[k]);
  *(float4*)(align_out + base) = make_float4(p[0], p[1], p[2], p[3]);
  *(float4*)(align_out + base + 4) = make_float4(p[4], p[5], p[6], p[7]);
}

// ---------------- K4: contexts = alignments . memory (atomic accumulate) ----------
// 512 WGs: wg -> (b, 128-row chunk); each half-WG does 64 rows x full E.
// Unroll-4 with batched loads: 4 float4 + 4 align scalars in flight per thread.
__global__ __launch_bounds__(256) void ctx_kernel(
    const float* __restrict__ memory, const float* __restrict__ align,
    float* __restrict__ ctx_out) {
  const int wg = blockIdx.x, tid = threadIdx.x;
  const int b = wg >> 4;
  const int t0 = (wg & 15) * 128 + (tid >> 7) * 64;
  const int col = (tid & 127) * 4;
  const float* mrow = memory + ((size_t)(b * T_ + t0)) * E_ + col;
  const float* arow = align + b * T_ + t0;
  float4 a = make_float4(0.f, 0.f, 0.f, 0.f);
  for (int t = 0; t < 64; t += 4) {
    float4 m0 = *(const float4*)(mrow + (size_t)(t + 0) * E_);
    float4 m1 = *(const float4*)(mrow + (size_t)(t + 1) * E_);
    float4 m2 = *(const float4*)(mrow + (size_t)(t + 2) * E_);
    float4 m3 = *(const float4*)(mrow + (size_t)(t + 3) * E_);
    float a0 = arow[t], a1 = arow[t + 1], a2 = arow[t + 2], a3 = arow[t + 3];
    a.x = fmaf(a0, m0.x, a.x); a.y = fmaf(a0, m0.y, a.y);
    a.z = fmaf(a0, m0.z, a.z); a.w = fmaf(a0, m0.w, a.w);
    a.x = fmaf(a1, m1.x, a.x); a.y = fmaf(a1, m1.y, a.y);
    a.z = fmaf(a1, m1.z, a.z); a.w = fmaf(a1, m1.w, a.w);
    a.x = fmaf(a2, m2.x, a.x); a.y = fmaf(a2, m2.y, a.y);
    a.z = fmaf(a2, m2.z, a.z); a.w = fmaf(a2, m2.w, a.w);
    a.x = fmaf(a3, m3.x, a.x); a.y = fmaf(a3, m3.y, a.y);
    a.z = fmaf(a3, m3.z, a.z); a.w = fmaf(a3, m3.w, a.w);
  }
  float* dst = ctx_out + b * E_ + col;
  atomicAdd(dst + 0, a.x);
  atomicAdd(dst + 1, a.y);
  atomicAdd(dst + 2, a.z);
  atomicAdd(dst + 3, a.w);
}

// ---------------- launch ----------------
extern "C" void kernel_launch(void* const* d_in, const int* in_sizes, int n_in,
                              void* d_out, int out_size, void* d_ws, size_t ws_size,
                              hipStream_t stream) {
  (void)in_sizes; (void)n_in; (void)out_size; (void)ws_size;
  const float* queries = (const float*)d_in[0];
  const float* prev    = (const float*)d_in[1];
  const float* memory  = (const float*)d_in[2];
  const float* Wq      = (const float*)d_in[3];
  const float* Wk      = (const float*)d_in[4];
  const float* v       = (const float*)d_in[5];

  float* out = (float*)d_out;
  float* ctx_out = out;              // [N,E]
  float* align_out = out + N_ * E_;  // [N,T]

  // ws layout (float slots): whiP [0,65536)  wloP [65536,131072)
  //   p_choose [131072,196608)  pq_part [196608,200704)
  float* ws = (float*)d_ws;
  bf16x8* whiP    = (bf16x8*)ws;
  bf16x8* wloP    = (bf16x8*)(ws + 65536);
  float* p_choose = ws + 131072;
  float* pq_part  = ws + 196608;

  prep_kernel<<<dim3(64 + 128), 256, 0, stream>>>(Wk, queries, Wq, whiP, wloP, pq_part);
  score_kernel<<<dim3(T_ / 128, N_), 256, 0, stream>>>(memory, whiP, wloP, pq_part, v, p_choose);
  scan_kernel<<<dim3(N_), 256, 0, stream>>>(p_choose, prev, align_out, ctx_out);
  ctx_kernel<<<dim3(512), 256, 0, stream>>>(memory, align_out, ctx_out);
}